// Round 10
// baseline (121.990 us; speedup 1.0000x reference)
//
#include <hip/hip_runtime.h>
#include <math.h>

// Problem constants
#define BATCH 32
#define HHWW  12544          // 112*112
#define CH    96
#define CH4   24             // CH/4
#define CR    24             // reduced channels
#define NBLK  28             // slices per batch
#define ROWS_PER_BLK (HHWW / NBLK)   // 448
#define RDIM  16             // row-threads per block

typedef float f32x4 __attribute__((ext_vector_type(4)));

// ws layout:
//   partial [BATCH][NBLK][CH] f32 : 344064 B

// ---------------------------------------------------------------------------
// Kernel 1: pool partials — verbatim R2-proven body, NO atomics (R7/R9
// lesson: per-block agent-scope atomics emit wbl2/inv that collapse BW).
// grid = (BATCH, NBLK), block (24,16) = 384 threads.
// ---------------------------------------------------------------------------
__global__ void __launch_bounds__(384)
se_pool_partial(const float* __restrict__ in,
                float* __restrict__ partial) {
    const int b   = blockIdx.x;
    const int blk = blockIdx.y;
    const int q   = threadIdx.x;   // 0..23 channel quad
    const int r   = threadIdx.y;   // 0..15 row lane

    const f32x4* inb = (const f32x4*)(in) + (size_t)b * HHWW * CH4;

    f32x4 acc = (f32x4)(0.f);
    const int row0 = blk * ROWS_PER_BLK;
    #pragma unroll 4
    for (int row = row0 + r; row < row0 + ROWS_PER_BLK; row += RDIM)
        acc += inb[(size_t)row * CH4 + q];

    __shared__ f32x4 sdata[RDIM][CH4];
    sdata[r][q] = acc;
    __syncthreads();
    if (r == 0) {
        f32x4 s = sdata[0][q];
        #pragma unroll
        for (int k = 1; k < RDIM; ++k) s += sdata[k][q];
        ((f32x4*)partial)[((size_t)b * NBLK + blk) * CH4 + q] = s;
    }
}

// ---------------------------------------------------------------------------
// Kernel 2: fused gate + scale, LOAD-FIRST ordering (fixes R3's serial-gate
// regression). grid = (49, BATCH), block 256, 24 float4/thread.
//
// Order per block:
//   1. issue all 24 input global loads into static-indexed v[24] (96 VGPR,
//      stays in flight — __syncthreads only waits lgkmcnt, not vmcnt)
//   2. compute gate[96] from the 28 partials (L2-hit loads + tiny matmuls)
//      -> fully hidden under the ~4 µs HBM drain of step 1
//   3. multiply + coherent NT store (proven R2 store flavor)
// ---------------------------------------------------------------------------
__global__ void __launch_bounds__(256)
se_gate_scale(const f32x4* __restrict__ in,
              const float* __restrict__ partial,   // [BATCH][NBLK][CH]
              const float* __restrict__ w_reduce,  // [CH][CR]
              const float* __restrict__ b_reduce,  // [CR]
              const float* __restrict__ w_expand,  // [CR][CH]
              const float* __restrict__ b_expand,  // [CH]
              f32x4* __restrict__ out)
{
    const int b = blockIdx.y;
    const int t = threadIdx.x;

    const size_t boff = (size_t)b * (HHWW * CH4);
    const int idx0 = blockIdx.x * 6144 + t;

    // ---- step 1: issue all 24 loads (static indices -> registers) ----
    f32x4 v0  = in[boff + idx0 +  0*256];
    f32x4 v1  = in[boff + idx0 +  1*256];
    f32x4 v2  = in[boff + idx0 +  2*256];
    f32x4 v3  = in[boff + idx0 +  3*256];
    f32x4 v4  = in[boff + idx0 +  4*256];
    f32x4 v5  = in[boff + idx0 +  5*256];
    f32x4 v6  = in[boff + idx0 +  6*256];
    f32x4 v7  = in[boff + idx0 +  7*256];
    f32x4 v8  = in[boff + idx0 +  8*256];
    f32x4 v9  = in[boff + idx0 +  9*256];
    f32x4 v10 = in[boff + idx0 + 10*256];
    f32x4 v11 = in[boff + idx0 + 11*256];
    f32x4 v12 = in[boff + idx0 + 12*256];
    f32x4 v13 = in[boff + idx0 + 13*256];
    f32x4 v14 = in[boff + idx0 + 14*256];
    f32x4 v15 = in[boff + idx0 + 15*256];
    f32x4 v16 = in[boff + idx0 + 16*256];
    f32x4 v17 = in[boff + idx0 + 17*256];
    f32x4 v18 = in[boff + idx0 + 18*256];
    f32x4 v19 = in[boff + idx0 + 19*256];
    f32x4 v20 = in[boff + idx0 + 20*256];
    f32x4 v21 = in[boff + idx0 + 21*256];
    f32x4 v22 = in[boff + idx0 + 22*256];
    f32x4 v23 = in[boff + idx0 + 23*256];

    // ---- step 2: gate compute (hides under the load drain) ----
    __shared__ float pooled[CH];
    __shared__ float hsw[CR];
    __shared__ float gateS[CH];

    if (t < CH) {
        float s = 0.f;
        #pragma unroll
        for (int k = 0; k < NBLK; ++k)
            s += partial[((size_t)b * NBLK + k) * CH + t];
        pooled[t] = s * (1.0f / (float)HHWW);
    }
    __syncthreads();
    if (t < CR) {
        float h = b_reduce[t];
        #pragma unroll
        for (int i = 0; i < CH; ++i)
            h += pooled[i] * w_reduce[i * CR + t];
        hsw[t] = h / (1.0f + expf(-h));   // swish
    }
    __syncthreads();
    if (t < CH) {
        float g = b_expand[t];
        #pragma unroll
        for (int j = 0; j < CR; ++j)
            g += hsw[j] * w_expand[j * CH + t];
        gateS[t] = 1.0f / (1.0f + expf(-g));
    }
    __syncthreads();

    // ---- step 3: multiply + NT store ----
    // quad of (idx0 + k*256) cycles with period 3: q0, q0+16, q0+8 (mod 24)
    const int q0 = t % CH4;
    const f32x4* g4 = (const f32x4*)gateS;
    const f32x4 g0 = g4[q0];
    const f32x4 g1 = g4[(q0 + 16) % CH4];
    const f32x4 g2 = g4[(q0 + 8) % CH4];

    f32x4* o = out + boff + idx0;
    __builtin_nontemporal_store(v0  * g0, o +  0*256);
    __builtin_nontemporal_store(v1  * g1, o +  1*256);
    __builtin_nontemporal_store(v2  * g2, o +  2*256);
    __builtin_nontemporal_store(v3  * g0, o +  3*256);
    __builtin_nontemporal_store(v4  * g1, o +  4*256);
    __builtin_nontemporal_store(v5  * g2, o +  5*256);
    __builtin_nontemporal_store(v6  * g0, o +  6*256);
    __builtin_nontemporal_store(v7  * g1, o +  7*256);
    __builtin_nontemporal_store(v8  * g2, o +  8*256);
    __builtin_nontemporal_store(v9  * g0, o +  9*256);
    __builtin_nontemporal_store(v10 * g1, o + 10*256);
    __builtin_nontemporal_store(v11 * g2, o + 11*256);
    __builtin_nontemporal_store(v12 * g0, o + 12*256);
    __builtin_nontemporal_store(v13 * g1, o + 13*256);
    __builtin_nontemporal_store(v14 * g2, o + 14*256);
    __builtin_nontemporal_store(v15 * g0, o + 15*256);
    __builtin_nontemporal_store(v16 * g1, o + 16*256);
    __builtin_nontemporal_store(v17 * g2, o + 17*256);
    __builtin_nontemporal_store(v18 * g0, o + 18*256);
    __builtin_nontemporal_store(v19 * g1, o + 19*256);
    __builtin_nontemporal_store(v20 * g2, o + 20*256);
    __builtin_nontemporal_store(v21 * g0, o + 21*256);
    __builtin_nontemporal_store(v22 * g1, o + 22*256);
    __builtin_nontemporal_store(v23 * g2, o + 23*256);
}

extern "C" void kernel_launch(void* const* d_in, const int* in_sizes, int n_in,
                              void* d_out, int out_size, void* d_ws, size_t ws_size,
                              hipStream_t stream) {
    const float* in       = (const float*)d_in[0];
    const float* w_reduce = (const float*)d_in[1];
    const float* b_reduce = (const float*)d_in[2];
    const float* w_expand = (const float*)d_in[3];
    const float* b_expand = (const float*)d_in[4];
    f32x4* out = (f32x4*)d_out;

    float* partial = (float*)d_ws;   // [BATCH][NBLK][CH]

    dim3 gridA(BATCH, NBLK);
    dim3 blockA(CH4, RDIM);
    se_pool_partial<<<gridA, blockA, 0, stream>>>(in, partial);

    dim3 gridB(49, BATCH);           // 49*6144 float4 = HHWW*CH4 per batch
    se_gate_scale<<<gridB, 256, 0, stream>>>((const f32x4*)in, partial,
                                             w_reduce, b_reduce,
                                             w_expand, b_expand, out);
}